// Round 1
// baseline (265.971 us; speedup 1.0000x reference)
//
#include <hip/hip_runtime.h>

#define HH 128
#define WW 128
#define CC 64
#define OO 64
#define NC 35
#define NPIX (HH*WW)        // per-batch pixels = 16384
#define LISTST NPIX
#define NBKT (2*NC)         // 70 buckets (b,label)
#define MV_WAVES 2048       // 512 blocks x 4 waves

// Workspace layout (needs ~24 MiB; harness ws is 256 MiB):
//   [0,    280)   cnt[70]      (memset to 0)
//   [1024, 1536)  gsum[128]    (memset to 0)
//   [2048, 2560)  gss[128]     (memset to 0)
//   [4096, ...)   list[70*16384] int   (bucketed per-b pixel ids)
//   [ 8 MiB)      xT : (b,pix,c) = x + conv-scalar, pixel-major
//   [16 MiB)      yT : (b,pix,o) pre-norm output, pixel-major

// Kernel 1: conv scalar + argmax + transpose x (+s) to pixel-major + bin pixels by (b,label)
__global__ __launch_bounds__(256) void prep_kernel(
    const float* __restrict__ x, const float* __restrict__ layout,
    const float* __restrict__ pr, const float* __restrict__ cw,
    const float* __restrict__ cb, const float* __restrict__ pl,
    float* __restrict__ xT, int* __restrict__ cnt, int* __restrict__ list)
{
    __shared__ float s_xh[64*33];   // [c][p] stride 33, conflict-free
    __shared__ float s_s[32];
    __shared__ int   s_arg[32];

    const int t    = threadIdx.x;
    const int wv   = t >> 6;
    const int lane = t & 63;
    const int tile = blockIdx.x;     // 1024: b(2) x h(128) x wq(4)
    const int b    = tile >> 9;
    const int rem  = tile & 511;
    const int h    = rem >> 2;
    const int w0   = (rem & 3) << 5;

    // conv scalar s for 32 pixels (wave 0, lanes 0..31)
    if (wv == 0 && lane < 32) {
        int w = w0 + lane;
        float pxv = (float)h * (2.0f/128.0f) - 1.0f;
        float pyv = (float)w * (2.0f/128.0f) - 1.0f;
        float pl0 = pl[h*WW + w];
        float pl1 = pl[NPIX + h*WW + w];
        float pr0 = pr[((b*2+0)*HH + h)*WW + w];
        float pr1 = pr[((b*2+1)*HH + h)*WW + w];
        int kx = w % 3, kyy = h % 3;
        const float C1 = -0.5f, S1 = 0.86602540378443864676f;
        float xcv = (kx==0)  ? 1.0f : C1;
        float xsv = (kx==0)  ? 0.0f : ((kx==1)  ? S1 : -S1);
        float ycv = (kyy==0) ? 1.0f : C1;
        float ysv = (kyy==0) ? 0.0f : ((kyy==1) ? S1 : -S1);
        s_s[lane] = cb[0] + pxv*cw[0] + pyv*cw[1] + pl0*cw[2] + pl1*cw[3]
                  + pr0*cw[4] + pr1*cw[5] + xcv*cw[6] + xsv*cw[7]
                  + ycv*cw[8] + ysv*cw[9];
    }

    // argmax over layout channels (wave 1, lanes 0..31); first-max wins like jnp.argmax
    if (wv == 1 && lane < 32) {
        int w = w0 + lane;
        const float* lp = layout + ((size_t)(b*NC)*HH + h)*WW + w;
        float best = lp[0]; int bi = 0;
        #pragma unroll
        for (int c = 1; c < NC; ++c) {
            float v = lp[(size_t)c*NPIX];
            if (v > best) { best = v; bi = c; }
        }
        s_arg[lane] = bi;
    }

    // stage raw x into LDS (coalesced)
    {
        int p = t & 31, c0 = t >> 5;
        const float* xp = x + ((size_t)(b*CC)*HH + h)*WW + w0 + p;
        #pragma unroll
        for (int k = 0; k < 8; ++k) {
            int c = c0 + 8*k;
            s_xh[c*33 + p] = xp[(size_t)c*NPIX];
        }
    }
    __syncthreads();

    // transpose-write xT[pix][c] = x + s  (coalesced 8 KB/block contiguous)
    {
        int p = t >> 3, c0 = (t & 7) << 3;
        float sp = s_s[p];
        float4 a, d;
        a.x = s_xh[(c0+0)*33+p] + sp;
        a.y = s_xh[(c0+1)*33+p] + sp;
        a.z = s_xh[(c0+2)*33+p] + sp;
        a.w = s_xh[(c0+3)*33+p] + sp;
        d.x = s_xh[(c0+4)*33+p] + sp;
        d.y = s_xh[(c0+5)*33+p] + sp;
        d.z = s_xh[(c0+6)*33+p] + sp;
        d.w = s_xh[(c0+7)*33+p] + sp;
        float* dst = xT + (((size_t)b*NPIX + h*WW + w0 + p) << 6) + c0;
        *(float4*)dst       = a;
        *(float4*)(dst + 4) = d;
    }

    // bin pixels into (b,label) buckets
    if (t < 32) {
        int l   = s_arg[t];
        int bkt = b*NC + l;
        int idx = atomicAdd(&cnt[bkt], 1);
        list[bkt*LISTST + idx] = h*WW + w0 + t;   // per-b pixel id
    }
}

// Kernel 2: label-grouped matvec. Task = (64-pixel single-label chunk) x (o-half of 32).
// Pixel-per-lane: lane owns its pixel's xh[64] in VGPRs; W reads are wave-uniform
// (readfirstlane'd label -> scalar/broadcast, L1-resident 16 KB) -> inner loop is pure FMA.
__global__ __launch_bounds__(256, 2) void mv_kernel(
    const float* __restrict__ Wt, const float* __restrict__ bt,
    const float* __restrict__ xT, const int* __restrict__ cnt,
    const int* __restrict__ list, float* __restrict__ yT,
    float* __restrict__ gsum, float* __restrict__ gss)
{
    const int t    = threadIdx.x;
    const int lane = t & 63;
    const int wgid = __builtin_amdgcn_readfirstlane(blockIdx.x * 4 + (t >> 6));

    // global max bucket count -> tight bound on chunk space (kills dead scan iters)
    int c1 = cnt[(lane < NBKT) ? lane : (NBKT-1)];
    int c2 = cnt[(lane < (NBKT-64)) ? 64 + lane : (NBKT-1)];
    int m  = c1 > c2 ? c1 : c2;
    #pragma unroll
    for (int d_ = 32; d_ >= 1; d_ >>= 1) {
        int o = __shfl_xor(m, d_);
        m = m > o ? m : o;
    }
    const int maxch = __builtin_amdgcn_readfirstlane((m + 63) >> 6);
    const int ntask = 2 * NBKT * maxch;    // half-major within (chunk-major x bucket)

    for (int task = wgid; task < ntask; task += MV_WAVES) {
        const int half  = task & 1;
        const int vc    = task >> 1;
        const int bkt   = vc % NBKT;       // chunk-major keeps active tasks contiguous
        const int chunk = vc / NBKT;
        const int n     = cnt[bkt];
        const int base  = chunk << 6;
        if (base >= n) continue;           // wave-uniform branch
        const int b = (bkt >= NC) ? 1 : 0;
        const int l = bkt - b * NC;

        const int  pi    = base + lane;
        const bool valid = pi < n;
        const float mask = valid ? 1.0f : 0.0f;
        const int  pib   = list[bkt*LISTST + (valid ? pi : base)];

        // gather this lane's pixel: 64 floats (lines fully consumed, no overfetch)
        const float* __restrict__ xp = xT + (((size_t)b*NPIX + pib) << 6);
        float xh[64];
        #pragma unroll
        for (int q = 0; q < 16; ++q) {
            float4 v = ((const float4*)xp)[q];
            xh[4*q+0] = v.x * mask;
            xh[4*q+1] = v.y * mask;
            xh[4*q+2] = v.z * mask;
            xh[4*q+3] = v.w * mask;
        }

        const float* __restrict__ Wl = Wt + (size_t)l * 4096;
        const float* __restrict__ bl = bt + l * 64;

        #pragma unroll
        for (int pp = 0; pp < 2; ++pp) {
            const int o0 = (half << 5) + (pp << 4);
            float acc[16];
            #pragma unroll
            for (int k = 0; k < 16; ++k) acc[k] = 0.0f;
            #pragma unroll
            for (int c = 0; c < 64; ++c) {
                const float xv = xh[c];
                const float4* __restrict__ wr = (const float4*)(Wl + c*64 + o0);
                float4 wa = wr[0], wb = wr[1], wc = wr[2], wd = wr[3];
                acc[ 0] = fmaf(xv, wa.x, acc[ 0]);
                acc[ 1] = fmaf(xv, wa.y, acc[ 1]);
                acc[ 2] = fmaf(xv, wa.z, acc[ 2]);
                acc[ 3] = fmaf(xv, wa.w, acc[ 3]);
                acc[ 4] = fmaf(xv, wb.x, acc[ 4]);
                acc[ 5] = fmaf(xv, wb.y, acc[ 5]);
                acc[ 6] = fmaf(xv, wb.z, acc[ 6]);
                acc[ 7] = fmaf(xv, wb.w, acc[ 7]);
                acc[ 8] = fmaf(xv, wc.x, acc[ 8]);
                acc[ 9] = fmaf(xv, wc.y, acc[ 9]);
                acc[10] = fmaf(xv, wc.z, acc[10]);
                acc[11] = fmaf(xv, wc.w, acc[11]);
                acc[12] = fmaf(xv, wd.x, acc[12]);
                acc[13] = fmaf(xv, wd.y, acc[13]);
                acc[14] = fmaf(xv, wd.z, acc[14]);
                acc[15] = fmaf(xv, wd.w, acc[15]);
            }
            // bias (wave-uniform), mask invalid lanes to 0 so stats stay clean
            float y[16];
            #pragma unroll
            for (int q = 0; q < 4; ++q) {
                float4 bb = ((const float4*)(bl + o0))[q];
                y[4*q+0] = (acc[4*q+0] + bb.x) * mask;
                y[4*q+1] = (acc[4*q+1] + bb.y) * mask;
                y[4*q+2] = (acc[4*q+2] + bb.z) * mask;
                y[4*q+3] = (acc[4*q+3] + bb.w) * mask;
            }
            if (valid) {
                float* __restrict__ yp = yT + (((size_t)b*NPIX + pib) << 6) + o0;
                ((float4*)yp)[0] = make_float4(y[ 0], y[ 1], y[ 2], y[ 3]);
                ((float4*)yp)[1] = make_float4(y[ 4], y[ 5], y[ 6], y[ 7]);
                ((float4*)yp)[2] = make_float4(y[ 8], y[ 9], y[10], y[11]);
                ((float4*)yp)[3] = make_float4(y[12], y[13], y[14], y[15]);
            }
            // per-o cross-lane sum / sumsq -> 2 atomics per o (70-bucket contention only)
            #pragma unroll
            for (int k = 0; k < 16; ++k) {
                float sv = y[k];
                float sq = y[k]*y[k];
                #pragma unroll
                for (int d_ = 32; d_ >= 1; d_ >>= 1) {
                    sv += __shfl_xor(sv, d_);
                    sq += __shfl_xor(sq, d_);
                }
                if (lane == 0) {
                    atomicAdd(&gsum[(b<<6) + o0 + k], sv);
                    atomicAdd(&gss [(b<<6) + o0 + k], sq);
                }
            }
        }
    }
}

// Kernel 3: finalize stats per block (cheap: 128 L2 loads) + transpose yT -> out with
// instance-norm + leaky relu. Tile: 64 o x 64 w.
__global__ __launch_bounds__(256) void norm_kernel(
    const float* __restrict__ yT, const float* __restrict__ gsum,
    const float* __restrict__ gss, float* __restrict__ out)
{
    __shared__ float s_t[64*65];   // [o][w] pad 65
    __shared__ float s_mean[64];
    __shared__ float s_rstd[64];

    const int t    = threadIdx.x;
    const int tile = blockIdx.x;   // 512: b(2) x h(128) x wt(2)
    const int b    = tile >> 8;
    const int rem  = tile & 255;
    const int h    = rem >> 1;
    const int w0   = (rem & 1) << 6;

    if (t < 64) {
        const float invN = 1.0f/16384.0f;
        float mean = gsum[(b<<6)+t] * invN;
        float var  = gss [(b<<6)+t] * invN - mean*mean;
        s_mean[t] = mean;
        s_rstd[t] = rsqrtf(var + 1e-5f);
    }
    {
        const int p = t >> 2, q = t & 3;   // pixel in tile, o-quarter
        const float4* yp = (const float4*)(yT + (((size_t)b*NPIX + h*WW + w0 + p) << 6) + (q << 4));
        #pragma unroll
        for (int j = 0; j < 4; ++j) {
            float4 v = yp[j];
            int o = (q << 4) + (j << 2);
            s_t[(o+0)*65 + p] = v.x;
            s_t[(o+1)*65 + p] = v.y;
            s_t[(o+2)*65 + p] = v.z;
            s_t[(o+3)*65 + p] = v.w;
        }
    }
    __syncthreads();
    {
        const int o = t >> 2, q = t & 3;
        const float mean = s_mean[o];
        const float r    = s_rstd[o];
        float* op = out + (((size_t)(b*OO + o)*HH + h)*WW) + w0 + (q << 4);
        #pragma unroll
        for (int j = 0; j < 4; ++j) {
            int wq = (q << 4) + (j << 2);
            float4 v;
            v.x = s_t[o*65 + wq + 0];
            v.y = s_t[o*65 + wq + 1];
            v.z = s_t[o*65 + wq + 2];
            v.w = s_t[o*65 + wq + 3];
            float a_;
            a_ = (v.x - mean) * r; v.x = (a_ >= 0.f) ? a_ : 0.01f*a_;
            a_ = (v.y - mean) * r; v.y = (a_ >= 0.f) ? a_ : 0.01f*a_;
            a_ = (v.z - mean) * r; v.z = (a_ >= 0.f) ? a_ : 0.01f*a_;
            a_ = (v.w - mean) * r; v.w = (a_ >= 0.f) ? a_ : 0.01f*a_;
            ((float4*)op)[j] = v;
        }
    }
}

extern "C" void kernel_launch(void* const* d_in, const int* in_sizes, int n_in,
                              void* d_out, int out_size, void* d_ws, size_t ws_size,
                              hipStream_t stream) {
    const float* x      = (const float*)d_in[0];
    const float* layout = (const float*)d_in[1];
    const float* pr     = (const float*)d_in[2];
    const float* cw     = (const float*)d_in[3];
    const float* cb     = (const float*)d_in[4];
    const float* Wt     = (const float*)d_in[5];
    const float* bt     = (const float*)d_in[6];
    const float* pl     = (const float*)d_in[7];
    float* out = (float*)d_out;

    char*  ws   = (char*)d_ws;
    int*   cnt  = (int*)ws;
    float* gsum = (float*)(ws + 1024);
    float* gss  = (float*)(ws + 2048);
    int*   list = (int*)(ws + 4096);
    float* xT   = (float*)(ws + (8u  << 20));
    float* yT   = (float*)(ws + (16u << 20));

    hipMemsetAsync(d_ws, 0, 4096, stream);   // cnt + gsum + gss only
    prep_kernel<<<1024, 256, 0, stream>>>(x, layout, pr, cw, cb, pl, xT, cnt, list);
    mv_kernel  <<< 512, 256, 0, stream>>>(Wt, bt, xT, cnt, list, yT, gsum, gss);
    norm_kernel<<< 512, 256, 0, stream>>>(yT, gsum, gss, out);
}

// Round 3
// 164.149 us; speedup vs baseline: 1.6203x; 1.6203x over previous
//
#include <hip/hip_runtime.h>

#define HH 128
#define WW 128
#define CC 64
#define OO 64
#define NC 35
#define NPIX (HH*WW)        // per-batch pixels = 16384
#define LISTST NPIX
#define NBKT (2*NC)         // 70 buckets (b,label)
#define XSTR 68             // s_xh row stride: 64 pixels + 4 pad (conflict-free reads)

// Workspace layout:
//   [0,    280)   cnt[70]      (memset to 0)
//   [1024, 1536)  gsum[128]    (memset to 0)
//   [2048, 2560)  gss[128]     (memset to 0)
//   [4096, ...)   list[70*16384] int
//   [ 8 MiB)      xT : (b,pix,c) = x + conv-scalar, pixel-major
//   [16 MiB)      yT : (b,pix,o) pre-norm output, pixel-major

// Kernel 1: conv scalar + argmax + transpose x (+s) to pixel-major + bin pixels by (b,label)
__global__ __launch_bounds__(256) void prep_kernel(
    const float* __restrict__ x, const float* __restrict__ layout,
    const float* __restrict__ pr, const float* __restrict__ cw,
    const float* __restrict__ cb, const float* __restrict__ pl,
    float* __restrict__ xT, int* __restrict__ cnt, int* __restrict__ list)
{
    __shared__ float s_xh[64*33];   // [c][p] stride 33, 32 pixels -> conflict-free
    __shared__ float s_s[32];
    __shared__ int   s_arg[32];

    const int t    = threadIdx.x;
    const int wv   = t >> 6;
    const int lane = t & 63;
    const int tile = blockIdx.x;     // 1024: b(2) x h(128) x wq(4)
    const int b    = tile >> 9;
    const int rem  = tile & 511;
    const int h    = rem >> 2;
    const int w0   = (rem & 3) << 5;

    // conv scalar s for 32 pixels (wave 0, lanes 0..31)
    if (wv == 0 && lane < 32) {
        int w = w0 + lane;
        float pxv = (float)h * (2.0f/128.0f) - 1.0f;
        float pyv = (float)w * (2.0f/128.0f) - 1.0f;
        float pl0 = pl[h*WW + w];
        float pl1 = pl[NPIX + h*WW + w];
        float pr0 = pr[((b*2+0)*HH + h)*WW + w];
        float pr1 = pr[((b*2+1)*HH + h)*WW + w];
        int kx = w % 3, kyy = h % 3;
        const float C1 = -0.5f, S1 = 0.86602540378443864676f;
        float xcv = (kx==0)  ? 1.0f : C1;
        float xsv = (kx==0)  ? 0.0f : ((kx==1)  ? S1 : -S1);
        float ycv = (kyy==0) ? 1.0f : C1;
        float ysv = (kyy==0) ? 0.0f : ((kyy==1) ? S1 : -S1);
        s_s[lane] = cb[0] + pxv*cw[0] + pyv*cw[1] + pl0*cw[2] + pl1*cw[3]
                  + pr0*cw[4] + pr1*cw[5] + xcv*cw[6] + xsv*cw[7]
                  + ycv*cw[8] + ysv*cw[9];
    }

    // argmax over layout channels (wave 1, lanes 0..31); first-max wins like jnp.argmax
    if (wv == 1 && lane < 32) {
        int w = w0 + lane;
        const float* lp = layout + ((size_t)(b*NC)*HH + h)*WW + w;
        float best = lp[0]; int bi = 0;
        #pragma unroll
        for (int c = 1; c < NC; ++c) {
            float v = lp[(size_t)c*NPIX];
            if (v > best) { best = v; bi = c; }
        }
        s_arg[lane] = bi;
    }

    // stage raw x into LDS (coalesced)
    {
        int p = t & 31, c0 = t >> 5;
        const float* xp = x + ((size_t)(b*CC)*HH + h)*WW + w0 + p;
        #pragma unroll
        for (int k = 0; k < 8; ++k) {
            int c = c0 + 8*k;
            s_xh[c*33 + p] = xp[(size_t)c*NPIX];
        }
    }
    __syncthreads();

    // transpose-write xT[pix][c] = x + s  (coalesced 8 KB/block contiguous)
    {
        int p = t >> 3, c0 = (t & 7) << 3;
        float sp = s_s[p];
        float4 a, d;
        a.x = s_xh[(c0+0)*33+p] + sp;
        a.y = s_xh[(c0+1)*33+p] + sp;
        a.z = s_xh[(c0+2)*33+p] + sp;
        a.w = s_xh[(c0+3)*33+p] + sp;
        d.x = s_xh[(c0+4)*33+p] + sp;
        d.y = s_xh[(c0+5)*33+p] + sp;
        d.z = s_xh[(c0+6)*33+p] + sp;
        d.w = s_xh[(c0+7)*33+p] + sp;
        float* dst = xT + (((size_t)b*NPIX + h*WW + w0 + p) << 6) + c0;
        *(float4*)dst       = a;
        *(float4*)(dst + 4) = d;
    }

    // bin pixels into (b,label) buckets
    if (t < 32) {
        int l   = s_arg[t];
        int bkt = b*NC + l;
        int idx = atomicAdd(&cnt[bkt], 1);
        list[bkt*LISTST + idx] = h*WW + w0 + t;   // per-b pixel id
    }
}

#define FMA_PX(A, XV) \
    A.x = fmaf((XV), qv.x, A.x); \
    A.y = fmaf((XV), qv.y, A.y); \
    A.z = fmaf((XV), qv.z, A.z); \
    A.w = fmaf((XV), qv.w, A.w);

// Kernel 2: label-grouped matvec, BLOCK-level tasks.
// Task = (bucket, chunk of 64 pixels). Block stages 64 pixels transposed into LDS
// [c][p] (stride 68 = 64+4: float4 reads at rows 4tt+ihi hit disjoint bank quads;
// staging writes pixel-per-lane -> 2 lanes/bank, free). Whole-wave-per-8-pixels
// inner loop: each W float4 (global, L1-resident 16 KB since label is block-
// uniform) is reused for 8 pixels via broadcast LDS float4 reads.
// Lane (i15,ihi): o-quad 4*i15, c = 4*tt+ihi; shfl_xor(16,32) reduces c-subsets.
__global__ __launch_bounds__(256) void mv_kernel(
    const float* __restrict__ Wt, const float* __restrict__ bt,
    const float* __restrict__ xT, const int* __restrict__ cnt,
    const int* __restrict__ list, float* __restrict__ yT,
    float* __restrict__ gsum, float* __restrict__ gss)
{
    __shared__ __align__(16) float s_xh[64*XSTR];   // [c][p]
    __shared__ int   s_pib[64];
    __shared__ float s_red[4][64][2];
    __shared__ int   s_ntask;

    const int t    = threadIdx.x;
    const int wv   = t >> 6;
    const int lane = t & 63;
    const int i15  = lane & 15;
    const int ihi  = lane >> 4;

    // tight task bound from max bucket count (wave 0)
    if (t < 64) {
        int c1 = cnt[(lane < NBKT) ? lane : (NBKT-1)];
        int c2 = cnt[(lane < (NBKT-64)) ? 64 + lane : (NBKT-1)];
        int m  = c1 > c2 ? c1 : c2;
        #pragma unroll
        for (int d = 32; d >= 1; d >>= 1) {
            int o = __shfl_xor(m, d);
            m = m > o ? m : o;
        }
        if (lane == 0) s_ntask = NBKT * ((m + 63) >> 6);
    }
    __syncthreads();
    const int ntask = s_ntask;

    for (int task = blockIdx.x; task < ntask; task += gridDim.x) {
        const int bkt   = task % NBKT;       // bucket-fastest: chunk 0 of all buckets first
        const int chunk = task / NBKT;
        const int n     = cnt[bkt];
        const int base  = chunk << 6;
        if (base >= n) continue;             // block-uniform
        const int b = (bkt >= NC) ? 1 : 0;
        const int l = bkt - b*NC;

        __syncthreads();   // protect s_xh/s_red from previous task's readers

        // ---- stage 64 pixels transposed into s_xh[c][p] + pixel ids ----
        // pixel-per-lane: p = t&63, quarter q = t>>6 -> LDS write banks 2-way (free)
        {
            const int p   = t & 63;
            const int q   = t >> 6;
            const int pi  = base + p;
            const int pib = list[bkt*LISTST + ((pi < n) ? pi : (n-1))];
            if (q == 0) s_pib[p] = pib;
            const float* xp = xT + (((size_t)b*NPIX + pib) << 6) + (q << 4);
            #pragma unroll
            for (int j = 0; j < 4; ++j) {
                float4 v = ((const float4*)xp)[j];
                const int c = (q << 4) + (j << 2);
                s_xh[(c+0)*XSTR + p] = v.x;
                s_xh[(c+1)*XSTR + p] = v.y;
                s_xh[(c+2)*XSTR + p] = v.z;
                s_xh[(c+3)*XSTR + p] = v.w;
            }
        }
        __syncthreads();

        // ---- compute: wave wv owns pixels wv*16..wv*16+15, two groups of 8 ----
        const float4* __restrict__ W4 = ((const float4*)(Wt + (size_t)l*4096)) + lane;
        const float4 bb = *((const float4*)(bt + (size_t)l*64) + i15);
        float4 sumv = make_float4(0,0,0,0), ssv = make_float4(0,0,0,0);

        #pragma unroll
        for (int g = 0; g < 2; ++g) {
            const int p0 = (wv << 4) + (g << 3);
            float4 a[8];
            #pragma unroll
            for (int pj = 0; pj < 8; ++pj) a[pj] = make_float4(0,0,0,0);

            #pragma unroll
            for (int tt = 0; tt < 16; ++tt) {
                const float4 qv = W4[tt << 6];                 // c = 4tt+ihi, o-quad 4*i15
                const int    c  = (tt << 2) + ihi;
                const float4 xa = *(const float4*)&s_xh[c*XSTR + p0];      // pixels p0..p0+3
                const float4 xb = *(const float4*)&s_xh[c*XSTR + p0 + 4];  // pixels p0+4..p0+7
                FMA_PX(a[0], xa.x) FMA_PX(a[1], xa.y) FMA_PX(a[2], xa.z) FMA_PX(a[3], xa.w)
                FMA_PX(a[4], xb.x) FMA_PX(a[5], xb.y) FMA_PX(a[6], xb.z) FMA_PX(a[7], xb.w)
            }

            // reduce partial c-subsets across the 4 ihi row-groups
            #pragma unroll
            for (int pj = 0; pj < 8; ++pj) {
                a[pj].x += __shfl_xor(a[pj].x, 16); a[pj].y += __shfl_xor(a[pj].y, 16);
                a[pj].z += __shfl_xor(a[pj].z, 16); a[pj].w += __shfl_xor(a[pj].w, 16);
                a[pj].x += __shfl_xor(a[pj].x, 32); a[pj].y += __shfl_xor(a[pj].y, 32);
                a[pj].z += __shfl_xor(a[pj].z, 32); a[pj].w += __shfl_xor(a[pj].w, 32);
            }

            if (ihi == 0) {
                #pragma unroll
                for (int pj = 0; pj < 8; ++pj) {
                    const bool  vld = (base + p0 + pj) < n;      // uniform over active lanes
                    const float msk = vld ? 1.0f : 0.0f;
                    float y0 = (a[pj].x + bb.x) * msk;
                    float y1 = (a[pj].y + bb.y) * msk;
                    float y2 = (a[pj].z + bb.z) * msk;
                    float y3 = (a[pj].w + bb.w) * msk;
                    if (vld) {
                        float* yp = yT + (((size_t)b*NPIX + s_pib[p0+pj]) << 6) + (i15 << 2);
                        *(float4*)yp = make_float4(y0, y1, y2, y3);
                    }
                    sumv.x += y0; ssv.x += y0*y0;
                    sumv.y += y1; ssv.y += y1*y1;
                    sumv.z += y2; ssv.z += y2*y2;
                    sumv.w += y3; ssv.w += y3*y3;
                }
            }
        }

        if (ihi == 0) {
            const int o = i15 << 2;
            s_red[wv][o+0][0] = sumv.x; s_red[wv][o+0][1] = ssv.x;
            s_red[wv][o+1][0] = sumv.y; s_red[wv][o+1][1] = ssv.y;
            s_red[wv][o+2][0] = sumv.z; s_red[wv][o+2][1] = ssv.z;
            s_red[wv][o+3][0] = sumv.w; s_red[wv][o+3][1] = ssv.w;
        }
        __syncthreads();
        if (t < 64) {
            float S  = s_red[0][t][0] + s_red[1][t][0] + s_red[2][t][0] + s_red[3][t][0];
            float SS = s_red[0][t][1] + s_red[1][t][1] + s_red[2][t][1] + s_red[3][t][1];
            atomicAdd(&gsum[(b << 6) + t], S);
            atomicAdd(&gss [(b << 6) + t], SS);
        }
    }
}

// Kernel 3: finalize stats per block + transpose yT -> out with instance-norm + leaky relu.
__global__ __launch_bounds__(256) void norm_kernel(
    const float* __restrict__ yT, const float* __restrict__ gsum,
    const float* __restrict__ gss, float* __restrict__ out)
{
    __shared__ float s_t[64*65];   // [o][w] pad 65
    __shared__ float s_mean[64];
    __shared__ float s_rstd[64];

    const int t    = threadIdx.x;
    const int tile = blockIdx.x;   // 512: b(2) x h(128) x wt(2)
    const int b    = tile >> 8;
    const int rem  = tile & 255;
    const int h    = rem >> 1;
    const int w0   = (rem & 1) << 6;

    if (t < 64) {
        const float invN = 1.0f/16384.0f;
        float mean = gsum[(b<<6)+t] * invN;
        float var  = gss [(b<<6)+t] * invN - mean*mean;
        s_mean[t] = mean;
        s_rstd[t] = rsqrtf(var + 1e-5f);
    }
    {
        const int p = t >> 2, q = t & 3;   // pixel in tile, o-quarter
        const float4* yp = (const float4*)(yT + (((size_t)b*NPIX + h*WW + w0 + p) << 6) + (q << 4));
        #pragma unroll
        for (int j = 0; j < 4; ++j) {
            float4 v = yp[j];
            int o = (q << 4) + (j << 2);
            s_t[(o+0)*65 + p] = v.x;
            s_t[(o+1)*65 + p] = v.y;
            s_t[(o+2)*65 + p] = v.z;
            s_t[(o+3)*65 + p] = v.w;
        }
    }
    __syncthreads();
    {
        const int o = t >> 2, q = t & 3;
        const float mean = s_mean[o];
        const float r    = s_rstd[o];
        float* op = out + (((size_t)(b*OO + o)*HH + h)*WW) + w0 + (q << 4);
        #pragma unroll
        for (int j = 0; j < 4; ++j) {
            int wq = (q << 4) + (j << 2);
            float4 v;
            v.x = s_t[o*65 + wq + 0];
            v.y = s_t[o*65 + wq + 1];
            v.z = s_t[o*65 + wq + 2];
            v.w = s_t[o*65 + wq + 3];
            float a_;
            a_ = (v.x - mean) * r; v.x = (a_ >= 0.f) ? a_ : 0.01f*a_;
            a_ = (v.y - mean) * r; v.y = (a_ >= 0.f) ? a_ : 0.01f*a_;
            a_ = (v.z - mean) * r; v.z = (a_ >= 0.f) ? a_ : 0.01f*a_;
            a_ = (v.w - mean) * r; v.w = (a_ >= 0.f) ? a_ : 0.01f*a_;
            ((float4*)op)[j] = v;
        }
    }
}

extern "C" void kernel_launch(void* const* d_in, const int* in_sizes, int n_in,
                              void* d_out, int out_size, void* d_ws, size_t ws_size,
                              hipStream_t stream) {
    const float* x      = (const float*)d_in[0];
    const float* layout = (const float*)d_in[1];
    const float* pr     = (const float*)d_in[2];
    const float* cw     = (const float*)d_in[3];
    const float* cb     = (const float*)d_in[4];
    const float* Wt     = (const float*)d_in[5];
    const float* bt     = (const float*)d_in[6];
    const float* pl     = (const float*)d_in[7];
    float* out = (float*)d_out;

    char*  ws   = (char*)d_ws;
    int*   cnt  = (int*)ws;
    float* gsum = (float*)(ws + 1024);
    float* gss  = (float*)(ws + 2048);
    int*   list = (int*)(ws + 4096);
    float* xT   = (float*)(ws + (8u  << 20));
    float* yT   = (float*)(ws + (16u << 20));

    hipMemsetAsync(d_ws, 0, 4096, stream);   // cnt + gsum + gss only
    prep_kernel<<<1024, 256, 0, stream>>>(x, layout, pr, cw, cb, pl, xT, cnt, list);
    mv_kernel  <<<1024, 256, 0, stream>>>(Wt, bt, xT, cnt, list, yT, gsum, gss);
    norm_kernel<<< 512, 256, 0, stream>>>(yT, gsum, gss, out);
}

// Round 5
// 128.083 us; speedup vs baseline: 2.0766x; 1.2816x over previous
//
#include <hip/hip_runtime.h>

#define HH 128
#define WW 128
#define CC 64
#define OO 64
#define NC 35
#define NPIX (HH*WW)        // per-batch pixels = 16384
#define LISTST NPIX
#define NBKT (2*NC)         // 70 buckets (b,label)
#define XSTR 68             // s_xh row stride: 64 pixels + 4 pad (conflict-free reads)

// Workspace layout:
//   [0,     8192)   gpad[128][16]  one 64B line per (b,o): [0]=sum, [1]=sumsq  (memset)
//   [8192,  8472)   cnt[70]        written by bin_kernel (plain store)
//   [16384, 147456) lab[2*16384] int  argmax label per pixel
//   [256 KiB, +4.6 MiB) list[70*16384] int
//   [ 8 MiB)        xT : (b,pix,c) = x + conv-scalar, pixel-major
//   [16 MiB)        yT : (b,pix,o) pre-norm output, pixel-major

// Kernel 1: conv scalar + argmax -> lab[] + transpose x (+s) to pixel-major. NO atomics.
__global__ __launch_bounds__(256) void prep_kernel(
    const float* __restrict__ x, const float* __restrict__ layout,
    const float* __restrict__ pr, const float* __restrict__ cw,
    const float* __restrict__ cb, const float* __restrict__ pl,
    float* __restrict__ xT, int* __restrict__ lab)
{
    __shared__ float s_xh[64*33];   // [c][p] stride 33, 32 pixels -> conflict-free
    __shared__ float s_s[32];

    const int t    = threadIdx.x;
    const int wv   = t >> 6;
    const int lane = t & 63;
    const int tile = blockIdx.x;     // 1024: b(2) x h(128) x wq(4)
    const int b    = tile >> 9;
    const int rem  = tile & 511;
    const int h    = rem >> 2;
    const int w0   = (rem & 3) << 5;

    // conv scalar s for 32 pixels (wave 0, lanes 0..31)
    if (wv == 0 && lane < 32) {
        int w = w0 + lane;
        float pxv = (float)h * (2.0f/128.0f) - 1.0f;
        float pyv = (float)w * (2.0f/128.0f) - 1.0f;
        float pl0 = pl[h*WW + w];
        float pl1 = pl[NPIX + h*WW + w];
        float pr0 = pr[((b*2+0)*HH + h)*WW + w];
        float pr1 = pr[((b*2+1)*HH + h)*WW + w];
        int kx = w % 3, kyy = h % 3;
        const float C1 = -0.5f, S1 = 0.86602540378443864676f;
        float xcv = (kx==0)  ? 1.0f : C1;
        float xsv = (kx==0)  ? 0.0f : ((kx==1)  ? S1 : -S1);
        float ycv = (kyy==0) ? 1.0f : C1;
        float ysv = (kyy==0) ? 0.0f : ((kyy==1) ? S1 : -S1);
        s_s[lane] = cb[0] + pxv*cw[0] + pyv*cw[1] + pl0*cw[2] + pl1*cw[3]
                  + pr0*cw[4] + pr1*cw[5] + xcv*cw[6] + xsv*cw[7]
                  + ycv*cw[8] + ysv*cw[9];
    }

    // argmax over layout channels (wave 1, lanes 0..31); first-max wins like jnp.argmax
    if (wv == 1 && lane < 32) {
        int w = w0 + lane;
        const float* lp = layout + ((size_t)(b*NC)*HH + h)*WW + w;
        float best = lp[0]; int bi = 0;
        #pragma unroll
        for (int c = 1; c < NC; ++c) {
            float v = lp[(size_t)c*NPIX];
            if (v > best) { best = v; bi = c; }
        }
        lab[b*NPIX + h*WW + w] = bi;      // plain coalesced store
    }

    // stage raw x into LDS (coalesced)
    {
        int p = t & 31, c0 = t >> 5;
        const float* xp = x + ((size_t)(b*CC)*HH + h)*WW + w0 + p;
        #pragma unroll
        for (int k = 0; k < 8; ++k) {
            int c = c0 + 8*k;
            s_xh[c*33 + p] = xp[(size_t)c*NPIX];
        }
    }
    __syncthreads();

    // transpose-write xT[pix][c] = x + s  (coalesced 8 KB/block contiguous)
    {
        int p = t >> 3, c0 = (t & 7) << 3;
        float sp = s_s[p];
        float4 a, d;
        a.x = s_xh[(c0+0)*33+p] + sp;
        a.y = s_xh[(c0+1)*33+p] + sp;
        a.z = s_xh[(c0+2)*33+p] + sp;
        a.w = s_xh[(c0+3)*33+p] + sp;
        d.x = s_xh[(c0+4)*33+p] + sp;
        d.y = s_xh[(c0+5)*33+p] + sp;
        d.z = s_xh[(c0+6)*33+p] + sp;
        d.w = s_xh[(c0+7)*33+p] + sp;
        float* dst = xT + (((size_t)b*NPIX + h*WW + w0 + p) << 6) + c0;
        *(float4*)dst       = a;
        *(float4*)(dst + 4) = d;
    }
}

// Kernel 1b: bucket the pixels. One block per (b,label) bucket. Coalesced interleaved
// scan; block-level shfl prefix-scan ranks matches; plain stores only (zero atomics).
__global__ __launch_bounds__(256) void bin_kernel(
    const int* __restrict__ lab, int* __restrict__ cnt, int* __restrict__ list)
{
    __shared__ int s_wsum[4];
    const int t    = threadIdx.x;
    const int lane = t & 63;
    const int wv   = t >> 6;
    const int bkt  = blockIdx.x;        // 0..69
    const int b    = (bkt >= NC) ? 1 : 0;
    const int l    = bkt - b*NC;
    const int* lp  = lab + b*NPIX;

    // pass 1: count matches (coalesced interleaved)
    int m = 0;
    #pragma unroll 8
    for (int j = 0; j < 64; ++j) m += (lp[j*256 + t] == l) ? 1 : 0;

    // inclusive wave scan -> exclusive block prefix
    int v = m;
    #pragma unroll
    for (int d = 1; d < 64; d <<= 1) {
        int o = __shfl_up(v, d);
        if (lane >= d) v += o;
    }
    if (lane == 63) s_wsum[wv] = v;
    __syncthreads();
    int wbase = 0;
    #pragma unroll
    for (int k = 0; k < 4; ++k) wbase += (k < wv) ? s_wsum[k] : 0;
    int base = wbase + v - m;           // exclusive prefix for this thread
    if (t == 0) cnt[bkt] = s_wsum[0] + s_wsum[1] + s_wsum[2] + s_wsum[3];

    // pass 2: scatter pixel ids
    int* dst = list + bkt*LISTST;
    int o = base;
    #pragma unroll 8
    for (int j = 0; j < 64; ++j) {
        int p = j*256 + t;
        if (lp[p] == l) dst[o++] = p;
    }
}

#define FMA_PX(A, XV) \
    A.x = fmaf((XV), qv.x, A.x); \
    A.y = fmaf((XV), qv.y, A.y); \
    A.z = fmaf((XV), qv.z, A.z); \
    A.w = fmaf((XV), qv.w, A.w);

// Kernel 2: label-grouped matvec, BLOCK-level tasks.
// Task = (bucket, chunk of 64 pixels). Stats go to gpad (one 64B line per (b,o))
// via fire-and-forget atomics -> pipelined, no shared-line serialization.
__global__ __launch_bounds__(256) void mv_kernel(
    const float* __restrict__ Wt, const float* __restrict__ bt,
    const float* __restrict__ xT, const int* __restrict__ cnt,
    const int* __restrict__ list, float* __restrict__ yT,
    float* __restrict__ gpad)
{
    __shared__ __align__(16) float s_xh[64*XSTR];   // [c][p]
    __shared__ int   s_pib[64];
    __shared__ float s_red[4][64][2];
    __shared__ int   s_ntask;

    const int t    = threadIdx.x;
    const int wv   = t >> 6;
    const int lane = t & 63;
    const int i15  = lane & 15;
    const int ihi  = lane >> 4;

    // tight task bound from max bucket count (wave 0)
    if (t < 64) {
        int c1 = cnt[(lane < NBKT) ? lane : (NBKT-1)];
        int c2 = cnt[(lane < (NBKT-64)) ? 64 + lane : (NBKT-1)];
        int m  = c1 > c2 ? c1 : c2;
        #pragma unroll
        for (int d = 32; d >= 1; d >>= 1) {
            int o = __shfl_xor(m, d);
            m = m > o ? m : o;
        }
        if (lane == 0) s_ntask = NBKT * ((m + 63) >> 6);
    }
    __syncthreads();
    const int ntask = s_ntask;

    for (int task = blockIdx.x; task < ntask; task += gridDim.x) {
        const int bkt   = task % NBKT;       // bucket-fastest: chunk 0 of all buckets first
        const int chunk = task / NBKT;
        const int n     = cnt[bkt];
        const int base  = chunk << 6;
        if (base >= n) continue;             // block-uniform
        const int b = (bkt >= NC) ? 1 : 0;
        const int l = bkt - b*NC;

        __syncthreads();   // protect s_xh/s_red from previous task's readers

        // ---- stage 64 pixels transposed into s_xh[c][p] + pixel ids ----
        {
            const int p   = t & 63;
            const int q   = t >> 6;
            const int pi  = base + p;
            const int pib = list[bkt*LISTST + ((pi < n) ? pi : (n-1))];
            if (q == 0) s_pib[p] = pib;
            const float* xp = xT + (((size_t)b*NPIX + pib) << 6) + (q << 4);
            #pragma unroll
            for (int j = 0; j < 4; ++j) {
                float4 v = ((const float4*)xp)[j];
                const int c = (q << 4) + (j << 2);
                s_xh[(c+0)*XSTR + p] = v.x;
                s_xh[(c+1)*XSTR + p] = v.y;
                s_xh[(c+2)*XSTR + p] = v.z;
                s_xh[(c+3)*XSTR + p] = v.w;
            }
        }
        __syncthreads();

        // ---- compute: wave wv owns pixels wv*16..wv*16+15, two groups of 8 ----
        const float4* __restrict__ W4 = ((const float4*)(Wt + (size_t)l*4096)) + lane;
        const float4 bb = *((const float4*)(bt + (size_t)l*64) + i15);
        float4 sumv = make_float4(0,0,0,0), ssv = make_float4(0,0,0,0);

        #pragma unroll
        for (int g = 0; g < 2; ++g) {
            const int p0 = (wv << 4) + (g << 3);
            float4 a[8];
            #pragma unroll
            for (int pj = 0; pj < 8; ++pj) a[pj] = make_float4(0,0,0,0);

            #pragma unroll
            for (int tt = 0; tt < 16; ++tt) {
                const float4 qv = W4[tt << 6];                 // c = 4tt+ihi, o-quad 4*i15
                const int    c  = (tt << 2) + ihi;
                const float4 xa = *(const float4*)&s_xh[c*XSTR + p0];      // pixels p0..p0+3
                const float4 xb = *(const float4*)&s_xh[c*XSTR + p0 + 4];  // pixels p0+4..p0+7
                FMA_PX(a[0], xa.x) FMA_PX(a[1], xa.y) FMA_PX(a[2], xa.z) FMA_PX(a[3], xa.w)
                FMA_PX(a[4], xb.x) FMA_PX(a[5], xb.y) FMA_PX(a[6], xb.z) FMA_PX(a[7], xb.w)
            }

            // reduce partial c-subsets across the 4 ihi row-groups
            #pragma unroll
            for (int pj = 0; pj < 8; ++pj) {
                a[pj].x += __shfl_xor(a[pj].x, 16); a[pj].y += __shfl_xor(a[pj].y, 16);
                a[pj].z += __shfl_xor(a[pj].z, 16); a[pj].w += __shfl_xor(a[pj].w, 16);
                a[pj].x += __shfl_xor(a[pj].x, 32); a[pj].y += __shfl_xor(a[pj].y, 32);
                a[pj].z += __shfl_xor(a[pj].z, 32); a[pj].w += __shfl_xor(a[pj].w, 32);
            }

            if (ihi == 0) {
                #pragma unroll
                for (int pj = 0; pj < 8; ++pj) {
                    const bool  vld = (base + p0 + pj) < n;      // uniform over active lanes
                    const float msk = vld ? 1.0f : 0.0f;
                    float y0 = (a[pj].x + bb.x) * msk;
                    float y1 = (a[pj].y + bb.y) * msk;
                    float y2 = (a[pj].z + bb.z) * msk;
                    float y3 = (a[pj].w + bb.w) * msk;
                    if (vld) {
                        float* yp = yT + (((size_t)b*NPIX + s_pib[p0+pj]) << 6) + (i15 << 2);
                        *(float4*)yp = make_float4(y0, y1, y2, y3);
                    }
                    sumv.x += y0; ssv.x += y0*y0;
                    sumv.y += y1; ssv.y += y1*y1;
                    sumv.z += y2; ssv.z += y2*y2;
                    sumv.w += y3; ssv.w += y3*y3;
                }
            }
        }

        if (ihi == 0) {
            const int o = i15 << 2;
            s_red[wv][o+0][0] = sumv.x; s_red[wv][o+0][1] = ssv.x;
            s_red[wv][o+1][0] = sumv.y; s_red[wv][o+1][1] = ssv.y;
            s_red[wv][o+2][0] = sumv.z; s_red[wv][o+2][1] = ssv.z;
            s_red[wv][o+3][0] = sumv.w; s_red[wv][o+3][1] = ssv.w;
        }
        __syncthreads();
        if (t < 64) {
            float S  = s_red[0][t][0] + s_red[1][t][0] + s_red[2][t][0] + s_red[3][t][0];
            float SS = s_red[0][t][1] + s_red[1][t][1] + s_red[2][t][1] + s_red[3][t][1];
            float* gp = gpad + (((b << 6) + t) << 4);   // private 64B line per (b,o)
            atomicAdd(gp + 0, S);                        // fire-and-forget (no return use)
            atomicAdd(gp + 1, SS);
        }
    }
}

// Kernel 3: finalize stats per block + transpose yT -> out with instance-norm + leaky relu.
__global__ __launch_bounds__(256) void norm_kernel(
    const float* __restrict__ yT, const float* __restrict__ gpad,
    float* __restrict__ out)
{
    __shared__ float s_t[64*65];   // [o][w] pad 65
    __shared__ float s_mean[64];
    __shared__ float s_rstd[64];

    const int t    = threadIdx.x;
    const int tile = blockIdx.x;   // 512: b(2) x h(128) x wt(2)
    const int b    = tile >> 8;
    const int rem  = tile & 255;
    const int h    = rem >> 1;
    const int w0   = (rem & 1) << 6;

    if (t < 64) {
        const float invN = 1.0f/16384.0f;
        const float* gp = gpad + (((b << 6) + t) << 4);
        float mean = gp[0] * invN;
        float var  = gp[1] * invN - mean*mean;
        s_mean[t] = mean;
        s_rstd[t] = rsqrtf(var + 1e-5f);
    }
    {
        const int p = t >> 2, q = t & 3;   // pixel in tile, o-quarter
        const float4* yp = (const float4*)(yT + (((size_t)b*NPIX + h*WW + w0 + p) << 6) + (q << 4));
        #pragma unroll
        for (int j = 0; j < 4; ++j) {
            float4 v = yp[j];
            int o = (q << 4) + (j << 2);
            s_t[(o+0)*65 + p] = v.x;
            s_t[(o+1)*65 + p] = v.y;
            s_t[(o+2)*65 + p] = v.z;
            s_t[(o+3)*65 + p] = v.w;
        }
    }
    __syncthreads();
    {
        const int o = t >> 2, q = t & 3;
        const float mean = s_mean[o];
        const float r    = s_rstd[o];
        float* op = out + (((size_t)(b*OO + o)*HH + h)*WW) + w0 + (q << 4);
        #pragma unroll
        for (int j = 0; j < 4; ++j) {
            int wq = (q << 4) + (j << 2);
            float4 v;
            v.x = s_t[o*65 + wq + 0];
            v.y = s_t[o*65 + wq + 1];
            v.z = s_t[o*65 + wq + 2];
            v.w = s_t[o*65 + wq + 3];
            float a_;
            a_ = (v.x - mean) * r; v.x = (a_ >= 0.f) ? a_ : 0.01f*a_;
            a_ = (v.y - mean) * r; v.y = (a_ >= 0.f) ? a_ : 0.01f*a_;
            a_ = (v.z - mean) * r; v.z = (a_ >= 0.f) ? a_ : 0.01f*a_;
            a_ = (v.w - mean) * r; v.w = (a_ >= 0.f) ? a_ : 0.01f*a_;
            ((float4*)op)[j] = v;
        }
    }
}

extern "C" void kernel_launch(void* const* d_in, const int* in_sizes, int n_in,
                              void* d_out, int out_size, void* d_ws, size_t ws_size,
                              hipStream_t stream) {
    const float* x      = (const float*)d_in[0];
    const float* layout = (const float*)d_in[1];
    const float* pr     = (const float*)d_in[2];
    const float* cw     = (const float*)d_in[3];
    const float* cb     = (const float*)d_in[4];
    const float* Wt     = (const float*)d_in[5];
    const float* bt     = (const float*)d_in[6];
    const float* pl     = (const float*)d_in[7];
    float* out = (float*)d_out;

    char*  ws   = (char*)d_ws;
    float* gpad = (float*)ws;                       // [128][16] f32, 8 KB (memset)
    int*   cnt  = (int*)(ws + 8192);                // [70]
    int*   lab  = (int*)(ws + 16384);               // [2][16384]
    int*   list = (int*)(ws + (256u << 10));        // [70][16384]
    float* xT   = (float*)(ws + (8u  << 20));
    float* yT   = (float*)(ws + (16u << 20));

    hipMemsetAsync(gpad, 0, 8192, stream);          // stats lines only
    prep_kernel<<<1024, 256, 0, stream>>>(x, layout, pr, cw, cb, pl, xT, lab);
    bin_kernel <<<  70, 256, 0, stream>>>(lab, cnt, list);
    mv_kernel  <<<1024, 256, 0, stream>>>(Wt, bt, xT, cnt, list, yT, gpad);
    norm_kernel<<< 512, 256, 0, stream>>>(yT, gpad, out);
}